// Round 4
// baseline (11563.409 us; speedup 1.0000x reference)
//
#include <hip/hip_runtime.h>

typedef _Float16 f16;
typedef _Float16 f16x8 __attribute__((ext_vector_type(8)));
typedef float f32x4 __attribute__((ext_vector_type(4)));

#define H_    256
#define TB_   128     // batch rows per workgroup
#define NT_   512     // threads per workgroup
#define SORB_ 64
#define SLOT_ 8192    // 32 rows * 256 cols, f16 -> 16 KB per slot

#define MFMA16(a, b, c) __builtin_amdgcn_mfma_f32_16x16x32_f16((a), (b), (c), 0, 0, 0)
#define UNR _Pragma("unroll")

__device__ __forceinline__ float sigm(float v) { return 1.0f / (1.0f + __expf(-v)); }
__device__ __forceinline__ float tanh_fast(float v) {
  float a = fabsf(v);
  float e = __expf(-2.0f * a);
  float t = (1.0f - e) / (1.0f + e);
  return copysignf(t, v);
}
// XOR-swizzle within a 32-row slot (f16 units, 16B granule): conflict-free b128 reads
__device__ __forceinline__ int lswz(int lrow, int col) {
  return lrow * H_ + (col ^ ((lrow & 7) << 3));
}

// fp32 -> f16 weight conversion: [whh0 | wih1 | whh1], each [768][256] row-major
__global__ void wcvt(const float* __restrict__ a, const float* __restrict__ b,
                     const float* __restrict__ c, f16* __restrict__ o) {
  int i = blockIdx.x * 256 + threadIdx.x;
  const int n = 768 * 256;
  if (i < n) {
    o[i]         = (f16)a[i];
    o[n + i]     = (f16)b[i];
    o[2 * n + i] = (f16)c[i];
  }
}

// ---- phase macros: read quarter from SRC slot, write h_new to TGT slot ----
// No value lives across any barrier; one __syncthreads per phase.
#define PHASE0(Q, SRC, TGT) do {                                              \
  const int _src = (SRC), _tgt = (TGT);                                       \
  UNR for (int nt = 0; nt < 2; ++nt) {                                        \
    const int col = wave * 32 + nt * 16 + l15;                                \
    f32x4 aR[2], aZ[2], aN[2];                                                \
    UNR for (int m = 0; m < 2; ++m) {                                         \
      aR[m] = (f32x4){0,0,0,0}; aZ[m] = aR[m]; aN[m] = aR[m];                 \
    }                                                                         \
    UNR for (int kt = 0; kt < 8; ++kt) {                                      \
      const int k0 = kt * 32 + lg * 8;                                        \
      const f16* wb = W16 + col * 256 + k0;                                   \
      f16x8 Br = *(const f16x8*)(wb);                                         \
      f16x8 Bz = *(const f16x8*)(wb + 65536);                                 \
      f16x8 Bn = *(const f16x8*)(wb + 131072);                                \
      UNR for (int m = 0; m < 2; ++m) {                                       \
        const int lrow = m * 16 + l15;                                        \
        f16x8 A = *(const f16x8*)&hall[_src + lswz(lrow, k0)];                \
        aR[m] = MFMA16(A, Br, aR[m]);                                         \
        aZ[m] = MFMA16(A, Bz, aZ[m]);                                         \
        aN[m] = MFMA16(A, Bn, aN[m]);                                         \
      }                                                                       \
    }                                                                         \
    UNR for (int m = 0; m < 2; ++m) {                                         \
      UNR for (int e = 0; e < 4; ++e) {                                       \
        const int lrow = m * 16 + lg * 4 + e;                                 \
        const int grow = (Q) * 32 + lrow;                                     \
        int cse = 0;                                                          \
        if (t >= 0) cse = 1 + ((bitsL[grow * 4 + (t >> 4)] >> (t & 15)) & 1); \
        const float* gt = &gi0T[cse * 768];                                   \
        float r  = sigm(aR[m][e] + gt[col]);                                  \
        float z  = sigm(aZ[m][e] + gt[256 + col]);                            \
        float n  = tanh_fast(gt[512 + col] + r * (aN[m][e] + bhh0n[col]));    \
        float ho = (float)hall[_src + lswz(lrow, col)];                       \
        hall[_tgt + lswz(lrow, col)] = (f16)((1.0f - z) * n + z * ho);        \
      }                                                                       \
    }                                                                         \
  }                                                                           \
  __syncthreads();                                                            \
} while (0)

#define PHASE1(Q, SRC0, SRC1, TGT) do {                                       \
  const int _s0 = (SRC0), _s1 = (SRC1), _tgt = (TGT);                         \
  UNR for (int nt = 0; nt < 2; ++nt) {                                        \
    const int col = wave * 32 + nt * 16 + l15;                                \
    f32x4 aR[2], aZ[2], aI[2], aHn[2];                                        \
    UNR for (int m = 0; m < 2; ++m) {                                         \
      aR[m] = (f32x4){0,0,0,0}; aZ[m] = aR[m]; aI[m] = aR[m]; aHn[m] = aR[m]; \
    }                                                                         \
    UNR for (int kt = 0; kt < 8; ++kt) {                                      \
      const int k0 = kt * 32 + lg * 8;                                        \
      const f16* wi = Wih1 + col * 256 + k0;                                  \
      const f16* wh = Whh1 + col * 256 + k0;                                  \
      f16x8 BiR = *(const f16x8*)(wi);                                        \
      f16x8 BiZ = *(const f16x8*)(wi + 65536);                                \
      f16x8 BiN = *(const f16x8*)(wi + 131072);                               \
      f16x8 BhR = *(const f16x8*)(wh);                                        \
      f16x8 BhZ = *(const f16x8*)(wh + 65536);                                \
      f16x8 BhN = *(const f16x8*)(wh + 131072);                               \
      UNR for (int m = 0; m < 2; ++m) {                                       \
        const int lrow = m * 16 + l15;                                        \
        f16x8 A0 = *(const f16x8*)&hall[_s0 + lswz(lrow, k0)];                \
        f16x8 A1 = *(const f16x8*)&hall[_s1 + lswz(lrow, k0)];                \
        aR[m]  = MFMA16(A0, BiR, aR[m]);  aR[m] = MFMA16(A1, BhR, aR[m]);     \
        aZ[m]  = MFMA16(A0, BiZ, aZ[m]);  aZ[m] = MFMA16(A1, BhZ, aZ[m]);     \
        aI[m]  = MFMA16(A0, BiN, aI[m]);                                      \
        aHn[m] = MFMA16(A1, BhN, aHn[m]);                                     \
      }                                                                       \
    }                                                                         \
    UNR for (int m = 0; m < 2; ++m) {                                         \
      UNR for (int e = 0; e < 4; ++e) {                                       \
        const int lrow = m * 16 + lg * 4 + e;                                 \
        float r = sigm(aR[m][e] + (float)bsum1h[col]);                        \
        float z = sigm(aZ[m][e] + (float)bsum1h[256 + col]);                  \
        float n = tanh_fast(aI[m][e] + (float)bsum1h[512 + col]               \
                            + r * (aHn[m][e] + bhh1n[col]));                  \
        float ho = (float)hall[_s1 + lswz(lrow, col)];                        \
        hall[_tgt + lswz(lrow, col)] = (f16)((1.0f - z) * n + z * ho);        \
      }                                                                       \
    }                                                                         \
  }                                                                           \
  __syncthreads();                                                            \
} while (0)

__global__ __launch_bounds__(NT_, 1) void rnnwf(
    const int* __restrict__ x,
    const float* __restrict__ w_ih0, const float* __restrict__ b_ih0,
    const float* __restrict__ b_hh0, const float* __restrict__ b_ih1,
    const float* __restrict__ b_hh1, const float* __restrict__ w_amp,
    const float* __restrict__ b_amp, const f16* __restrict__ W16,
    float* __restrict__ out)
{
  __shared__ __align__(16) f16 hall[9 * SLOT_];  // 144 KB: 8 state quarters + 1 spare
  __shared__ float gi0T[3 * 768];   // [prime, bit0, bit1][768]; b_hh0 folded for j<512
  __shared__ float bhh0n[256];
  __shared__ f16   bsum1h[768];     // b_ih1 (+b_hh1 for j<512), f16
  __shared__ float bhh1n[256];
  __shared__ f16   wampL[512];
  __shared__ unsigned short bitsL[TB_ * 4];

  const int tid  = threadIdx.x;
  const int wave = tid >> 6;
  const int lane = tid & 63;
  const int l15  = lane & 15;
  const int lg   = lane >> 4;
  const int rowbase = blockIdx.x * TB_;

  // ---- one-time setup ----
  for (int j = tid; j < 768; j += NT_) {
    float bi = b_ih0[j], bh = b_hh0[j];
    float base = bi + (j < 512 ? bh : 0.0f);
    gi0T[j]        = base;
    gi0T[768 + j]  = base + w_ih0[2 * j + 0];
    gi0T[1536 + j] = base + w_ih0[2 * j + 1];
    if (j >= 512) bhh0n[j - 512] = bh;
    bsum1h[j] = (f16)(b_ih1[j] + (j < 512 ? b_hh1[j] : 0.0f));
    if (j >= 512) bhh1n[j - 512] = b_hh1[j];
  }
  for (int j = tid; j < 512; j += NT_) wampL[j] = (f16)w_amp[j];
  const float ba0 = b_amp[0], ba1 = b_amp[1];
  {
    int row = tid >> 2, q = tid & 3;
    const int* xp = x + (size_t)(rowbase + row) * SORB_ + q * 16;
    unsigned m = 0;
    #pragma unroll
    for (int i = 0; i < 16; ++i) m |= (unsigned)(xp[i] & 1) << i;
    bitsL[row * 4 + q] = (unsigned short)m;
  }
  for (int i = tid; i < 9 * SLOT_; i += NT_) hall[i] = (f16)0.f;
  __syncthreads();

  float prob = 1.0f;
  const f16* Wih1 = W16 + 768 * 256;
  const f16* Whh1 = W16 + 2 * 768 * 256;

  // slot bases (element offsets); rotate via spare each phase
  int bh0[4] = {0, SLOT_, 2 * SLOT_, 3 * SLOT_};
  int bh1[4] = {4 * SLOT_, 5 * SLOT_, 6 * SLOT_, 7 * SLOT_};
  int sp = 8 * SLOT_;

  for (int t = -1; t < SORB_; ++t) {
    UNR for (int q = 0; q < 4; ++q) {
      PHASE0(q, bh0[q], sp);
      int tmp = bh0[q]; bh0[q] = sp; sp = tmp;
    }
    UNR for (int q = 0; q < 4; ++q) {
      PHASE1(q, bh0[q], bh1[q], sp);
      int tmp = bh1[q]; bh1[q] = sp; sp = tmp;
    }

    // ---- amplitude head ----
    if (t >= 0) {
      const int row  = tid >> 2;
      const int t4   = tid & 3;
      const int qh   = row >> 5;
      const int lrow = row & 31;
      const int hb = qh == 0 ? bh1[0] : qh == 1 ? bh1[1] : qh == 2 ? bh1[2] : bh1[3];
      float d0 = 0.f, d1 = 0.f;
      #pragma unroll
      for (int kk = 0; kk < 64; kk += 8) {
        const int k0 = t4 * 64 + kk;
        f16x8 hv = *(const f16x8*)&hall[hb + lswz(lrow, k0)];
        #pragma unroll
        for (int i = 0; i < 8; ++i) {
          float hf = (float)hv[i];
          d0 = fmaf(hf, (float)wampL[k0 + i], d0);
          d1 = fmaf(hf, (float)wampL[256 + k0 + i], d1);
        }
      }
      d0 += __shfl_xor(d0, 1); d0 += __shfl_xor(d0, 2);
      d1 += __shfl_xor(d1, 1); d1 += __shfl_xor(d1, 2);
      const int bit = (bitsL[row * 4 + (t >> 4)] >> (t & 15)) & 1;
      float diff = (d0 + ba0) - (d1 + ba1);
      if (bit) diff = -diff;
      prob *= 1.0f / (1.0f + __expf(-diff));
    }
  }

  if ((tid & 3) == 0) out[rowbase + (tid >> 2)] = sqrtf(prob);
}

extern "C" void kernel_launch(void* const* d_in, const int* in_sizes, int n_in,
                              void* d_out, int out_size, void* d_ws, size_t ws_size,
                              hipStream_t stream) {
  const int*   x     = (const int*)d_in[0];
  const float* w_ih0 = (const float*)d_in[1];
  const float* w_hh0 = (const float*)d_in[2];
  const float* b_ih0 = (const float*)d_in[3];
  const float* b_hh0 = (const float*)d_in[4];
  const float* w_ih1 = (const float*)d_in[5];
  const float* w_hh1 = (const float*)d_in[6];
  const float* b_ih1 = (const float*)d_in[7];
  const float* b_hh1 = (const float*)d_in[8];
  const float* w_amp = (const float*)d_in[9];
  const float* b_amp = (const float*)d_in[10];
  (void)in_sizes; (void)n_in; (void)out_size; (void)ws_size;

  f16* W16 = (f16*)d_ws;   // 3*768*256*2 = 1.18 MB of workspace
  hipLaunchKernelGGL(wcvt, dim3(768), dim3(256), 0, stream, w_hh0, w_ih1, w_hh1, W16);
  hipLaunchKernelGGL(rnnwf, dim3(256), dim3(NT_), 0, stream,
                     x, w_ih0, b_ih0, b_hh0, b_ih1, b_hh1, w_amp, b_amp, W16,
                     (float*)d_out);
}

// Round 5
// 8624.812 us; speedup vs baseline: 1.3407x; 1.3407x over previous
//
#include <hip/hip_runtime.h>

typedef _Float16 f16;
typedef _Float16 f16x8 __attribute__((ext_vector_type(8)));
typedef float f32x4 __attribute__((ext_vector_type(4)));

#define H_    256
#define TB_   64      // batch rows per workgroup
#define NT_   1024    // threads per workgroup (16 waves, 4 per SIMD)
#define SORB_ 64
#define SLOT_ 8192    // 32 rows * 256 cols f16 -> 16 KB; a pair (64 rows) = 2 slots

#define MFMA16(a, b, c) __builtin_amdgcn_mfma_f32_16x16x32_f16((a), (b), (c), 0, 0, 0)
#define UNR _Pragma("unroll")

__device__ __forceinline__ float sigm(float v) { return 1.0f / (1.0f + __expf(-v)); }
__device__ __forceinline__ float tanh_fast(float v) {
  float a = fabsf(v);
  float e = __expf(-2.0f * a);
  float t = (1.0f - e) / (1.0f + e);
  return copysignf(t, v);
}
// XOR-swizzle within a 32-row slot (f16 units, 16B granule): conflict-light b128 reads
__device__ __forceinline__ int lswz(int lrow, int col) {
  return lrow * H_ + (col ^ ((lrow & 7) << 3));
}

// fp32 -> f16 weight conversion: [whh0 | wih1 | whh1], each [768][256] row-major
__global__ void wcvt(const float* __restrict__ a, const float* __restrict__ b,
                     const float* __restrict__ c, f16* __restrict__ o) {
  int i = blockIdx.x * 256 + threadIdx.x;
  const int n = 768 * 256;
  if (i < n) {
    o[i]         = (f16)a[i];
    o[n + i]     = (f16)b[i];
    o[2 * n + i] = (f16)c[i];
  }
}

__global__ __launch_bounds__(NT_, 4) void rnnwf(
    const int* __restrict__ x,
    const float* __restrict__ w_ih0, const float* __restrict__ b_ih0,
    const float* __restrict__ b_hh0, const float* __restrict__ b_ih1,
    const float* __restrict__ b_hh1, const float* __restrict__ w_amp,
    const float* __restrict__ b_amp, const f16* __restrict__ W16,
    float* __restrict__ out)
{
  __shared__ __align__(16) f16 hall[6 * SLOT_];  // 96 KB: 3 pairs of 64 rows
  __shared__ float gi0T[3 * 768];   // [prime, bit0, bit1][768]; b_hh0 folded for j<512
  __shared__ float wampL[512];
  __shared__ unsigned short bitsL[TB_ * 4];

  const int tid  = threadIdx.x;
  const int wave = tid >> 6;                  // 0..15
  const int lane = tid & 63;
  const int l15  = lane & 15;
  const int lg   = lane >> 4;                 // 0..3
  const int col  = wave * 16 + l15;           // hidden-unit column owned by this thread
  const int rowbase = blockIdx.x * TB_;

  // ---- one-time setup ----
  for (int j = tid; j < 768; j += NT_) {
    float bi = b_ih0[j], bh = b_hh0[j];
    float base = bi + (j < 512 ? bh : 0.0f);
    gi0T[j]        = base;
    gi0T[768 + j]  = base + w_ih0[2 * j + 0];
    gi0T[1536 + j] = base + w_ih0[2 * j + 1];
  }
  for (int j = tid; j < 512; j += NT_) wampL[j] = w_amp[j];
  if (tid < 256) {
    int row = tid >> 2, q = tid & 3;
    const int* xp = x + (size_t)(rowbase + row) * SORB_ + q * 16;
    unsigned m = 0;
    #pragma unroll
    for (int i = 0; i < 16; ++i) m |= (unsigned)(xp[i] & 1) << i;
    bitsL[row * 4 + q] = (unsigned short)m;
  }
  for (int i = tid; i < 6 * SLOT_; i += NT_) hall[i] = (f16)0.f;

  // per-thread bias constants (replace LDS tables)
  const float bhh0n_c = b_hh0[512 + col];
  const float b1r_c   = b_ih1[col]       + b_hh1[col];
  const float b1z_c   = b_ih1[256 + col] + b_hh1[256 + col];
  const float b1ni_c  = b_ih1[512 + col];
  const float b1nh_c  = b_hh1[512 + col];
  const float ba0 = b_amp[0], ba1 = b_amp[1];
  __syncthreads();

  float prob = 1.0f;
  const f16* Wih1 = W16 + 768 * 256;
  const f16* Whh1 = W16 + 2 * 768 * 256;

  int pa = 0, pb = 2 * SLOT_, pc = 4 * SLOT_;   // h0_cur, h1_cur, free

  for (int t = -1; t < SORB_; ++t) {
    // ================= layer 0: read pa -> write pc =================
    {
      f32x4 aR[4], aZ[4], aN[4];
      UNR for (int m = 0; m < 4; ++m) { aR[m] = (f32x4){0,0,0,0}; aZ[m] = aR[m]; aN[m] = aR[m]; }
      UNR for (int kt = 0; kt < 8; ++kt) {
        const int k0 = kt * 32 + lg * 8;
        const f16* wb = W16 + col * 256 + k0;
        f16x8 Br = *(const f16x8*)(wb);
        f16x8 Bz = *(const f16x8*)(wb + 65536);
        f16x8 Bn = *(const f16x8*)(wb + 131072);
        UNR for (int m = 0; m < 4; ++m) {
          f16x8 A = *(const f16x8*)&hall[pa + (m >> 1) * SLOT_ + lswz((m & 1) * 16 + l15, k0)];
          aR[m] = MFMA16(A, Br, aR[m]);
          aZ[m] = MFMA16(A, Bz, aZ[m]);
          aN[m] = MFMA16(A, Bn, aN[m]);
        }
      }
      UNR for (int m = 0; m < 4; ++m) {
        UNR for (int e = 0; e < 4; ++e) {
          const int lrow = (m & 1) * 16 + lg * 4 + e;
          const int grow = m * 16 + lg * 4 + e;
          int cse = 0;
          if (t >= 0) cse = 1 + ((bitsL[grow * 4 + (t >> 4)] >> (t & 15)) & 1);
          const float* gt = &gi0T[cse * 768];
          float r  = sigm(aR[m][e] + gt[col]);
          float z  = sigm(aZ[m][e] + gt[256 + col]);
          float n  = tanh_fast(gt[512 + col] + r * (aN[m][e] + bhh0n_c));
          float ho = (float)hall[pa + (m >> 1) * SLOT_ + lswz(lrow, col)];
          hall[pc + (m >> 1) * SLOT_ + lswz(lrow, col)] = (f16)((1.0f - z) * n + z * ho);
        }
      }
    }
    __syncthreads();

    // ================= layer 1: read pc (h0_new) + pb (h1_old) -> write pa =================
    {
      f32x4 aR[4], aZ[4], aNi[4], aNh[4];
      UNR for (int m = 0; m < 4; ++m) { aR[m] = (f32x4){0,0,0,0}; aZ[m] = aR[m]; aNi[m] = aR[m]; aNh[m] = aR[m]; }
      // pass 1: input-hidden (A = h0_new in pc)
      UNR for (int kt = 0; kt < 8; ++kt) {
        const int k0 = kt * 32 + lg * 8;
        const f16* wi = Wih1 + col * 256 + k0;
        f16x8 BiR = *(const f16x8*)(wi);
        f16x8 BiZ = *(const f16x8*)(wi + 65536);
        f16x8 BiN = *(const f16x8*)(wi + 131072);
        UNR for (int m = 0; m < 4; ++m) {
          f16x8 A0 = *(const f16x8*)&hall[pc + (m >> 1) * SLOT_ + lswz((m & 1) * 16 + l15, k0)];
          aR[m]  = MFMA16(A0, BiR, aR[m]);
          aZ[m]  = MFMA16(A0, BiZ, aZ[m]);
          aNi[m] = MFMA16(A0, BiN, aNi[m]);
        }
      }
      // pass 2: hidden-hidden (A = h1_old in pb), r/z chained into same acc
      UNR for (int kt = 0; kt < 8; ++kt) {
        const int k0 = kt * 32 + lg * 8;
        const f16* wh = Whh1 + col * 256 + k0;
        f16x8 BhR = *(const f16x8*)(wh);
        f16x8 BhZ = *(const f16x8*)(wh + 65536);
        f16x8 BhN = *(const f16x8*)(wh + 131072);
        UNR for (int m = 0; m < 4; ++m) {
          f16x8 A1 = *(const f16x8*)&hall[pb + (m >> 1) * SLOT_ + lswz((m & 1) * 16 + l15, k0)];
          aR[m]  = MFMA16(A1, BhR, aR[m]);
          aZ[m]  = MFMA16(A1, BhZ, aZ[m]);
          aNh[m] = MFMA16(A1, BhN, aNh[m]);
        }
      }
      UNR for (int m = 0; m < 4; ++m) {
        UNR for (int e = 0; e < 4; ++e) {
          const int lrow = (m & 1) * 16 + lg * 4 + e;
          float r = sigm(aR[m][e] + b1r_c);
          float z = sigm(aZ[m][e] + b1z_c);
          float n = tanh_fast(aNi[m][e] + b1ni_c + r * (aNh[m][e] + b1nh_c));
          float ho = (float)hall[pb + (m >> 1) * SLOT_ + lswz(lrow, col)];
          hall[pa + (m >> 1) * SLOT_ + lswz(lrow, col)] = (f16)((1.0f - z) * n + z * ho);
        }
      }
    }
    __syncthreads();

    // ================= amplitude head (reads pa = h1_new; no extra barrier) =================
    if (t >= 0) {
      const int row = tid >> 4;            // 64 rows, 16 threads each
      const int t16 = tid & 15;
      float d0 = 0.f, d1 = 0.f;
      #pragma unroll
      for (int j = 0; j < 2; ++j) {
        const int k0 = t16 * 16 + j * 8;
        f16x8 hv = *(const f16x8*)&hall[pa + (row >> 5) * SLOT_ + lswz(row & 31, k0)];
        #pragma unroll
        for (int i = 0; i < 8; ++i) {
          float hf = (float)hv[i];
          d0 = fmaf(hf, wampL[k0 + i], d0);
          d1 = fmaf(hf, wampL[256 + k0 + i], d1);
        }
      }
      d0 += __shfl_xor(d0, 1); d0 += __shfl_xor(d0, 2);
      d0 += __shfl_xor(d0, 4); d0 += __shfl_xor(d0, 8);
      d1 += __shfl_xor(d1, 1); d1 += __shfl_xor(d1, 2);
      d1 += __shfl_xor(d1, 4); d1 += __shfl_xor(d1, 8);
      const int bit = (bitsL[row * 4 + (t >> 4)] >> (t & 15)) & 1;
      float diff = (d0 + ba0) - (d1 + ba1);
      if (bit) diff = -diff;
      prob *= 1.0f / (1.0f + __expf(-diff));
    }

    // rotate pairs: h0_cur := pc, h1_cur := pa, free := pb
    int tmp = pa; pa = pc; pc = pb; pb = tmp;
  }

  if ((tid & 15) == 0) out[rowbase + (tid >> 4)] = sqrtf(prob);
}

extern "C" void kernel_launch(void* const* d_in, const int* in_sizes, int n_in,
                              void* d_out, int out_size, void* d_ws, size_t ws_size,
                              hipStream_t stream) {
  const int*   x     = (const int*)d_in[0];
  const float* w_ih0 = (const float*)d_in[1];
  const float* w_hh0 = (const float*)d_in[2];
  const float* b_ih0 = (const float*)d_in[3];
  const float* b_hh0 = (const float*)d_in[4];
  const float* w_ih1 = (const float*)d_in[5];
  const float* w_hh1 = (const float*)d_in[6];
  const float* b_ih1 = (const float*)d_in[7];
  const float* b_hh1 = (const float*)d_in[8];
  const float* w_amp = (const float*)d_in[9];
  const float* b_amp = (const float*)d_in[10];
  (void)in_sizes; (void)n_in; (void)out_size; (void)ws_size;

  f16* W16 = (f16*)d_ws;   // 3*768*256*2 = 1.18 MB of workspace
  hipLaunchKernelGGL(wcvt, dim3(768), dim3(256), 0, stream, w_hh0, w_ih1, w_hh1, W16);
  hipLaunchKernelGGL(rnnwf, dim3(32768 / TB_), dim3(NT_), 0, stream,
                     x, w_ih0, b_ih0, b_hh0, b_ih1, b_hh1, w_amp, b_amp, W16,
                     (float*)d_out);
}